// Round 15
// baseline (267.455 us; speedup 1.0000x reference)
//
#include <hip/hip_runtime.h>
#include <math.h>

#define NN 11
#define RR 8192               // B*L positions
#define DD 1024
#define EPSV 1e-5f
#define PREP_TPB 256

// ---- ws layout (floats) ----
// wvec  : [22][1024] f32   @ 0
// scal  : [22][2]    f32   @ 22528 (padded to 64)
// wfrag : [32][2][64][8] bf16 @ 22592 (32768 shorts = 16384 float-slots)
// dots  : [24][11][8192]   @ 38976  (j: 0..21 dots, 22 sum(via ones-col), 23 ssq)
// pack  : [8192][264]      @ 2201664
#define OFF_SCAL 22528
#define OFF_WFRAG 22592
#define OFF_DOTS 38976
#define OFF_PACK 2201664

typedef __attribute__((ext_vector_type(8))) short short8;
typedef __attribute__((ext_vector_type(4))) float f32x4;

__device__ __forceinline__ float wave_reduce(float v) {
#pragma unroll
  for (int o = 32; o > 0; o >>= 1) v += __shfl_xor(v, o, 64);
  return v;
}

__device__ __forceinline__ float dot4(const float4 a, const float4 b) {
  return a.x*b.x + a.y*b.y + a.z*b.z + a.w*b.w;
}

__device__ __forceinline__ unsigned bf2(float a, float b) {
  unsigned ua = __float_as_uint(a), ub = __float_as_uint(b);
  ua = (ua + 0x7FFFu + ((ua >> 16) & 1u)) >> 16;
  ub = (ub + 0x7FFFu + ((ub >> 16) & 1u)) >> 16;
  return ua | (ub << 16);
}

__global__ __launch_bounds__(PREP_TPB) void prep_kernel(
    const float* __restrict__ aq, const float* __restrict__ ag, const float* __restrict__ ab,
    const float* __restrict__ mq, const float* __restrict__ mg, const float* __restrict__ mb,
    float* __restrict__ wvec, float* __restrict__ scal)
{
  const int j = blockIdx.x;              // 0..21
  const float *q, *g, *bt;
  if (j < NN) { q = aq + (size_t)j*DD;      g = ag + (size_t)j*DD;      bt = ab + (size_t)j*DD; }
  else        { q = mq + (size_t)(j-NN)*DD; g = mg + (size_t)(j-NN)*DD; bt = mb + (size_t)(j-NN)*DD; }
  const int t = threadIdx.x;
  float sqg = 0.f, sqb = 0.f;
  for (int d = t; d < DD; d += PREP_TPB) {
    float qq = q[d];
    float w  = qq * g[d];
    wvec[(size_t)j*DD + d] = w;
    sqg += w;
    sqb += qq * bt[d];
  }
  sqg = wave_reduce(sqg);
  sqb = wave_reduce(sqb);
  __shared__ float red[2][PREP_TPB/64];
  const int lane = t & 63, wid = t >> 6;
  if (lane == 0) { red[0][wid] = sqg; red[1][wid] = sqb; }
  __syncthreads();
  if (t == 0) {
    float a = 0.f, b2 = 0.f;
    for (int w = 0; w < PREP_TPB/64; ++w) { a += red[0][w]; b2 += red[1][w]; }
    scal[2*j]   = a;
    scal[2*j+1] = b2;
  }
}

// pack B fragments: wfrag[kstep][c][lane][e] = bf16(wvec[j][k]), j=c*16+(lane&15),
// k=kstep*32+(lane>>4)*8+e. j==22 -> 1.0 (ones column: row-sum rides the MFMA);
// other j>=22 -> 0.
__global__ __launch_bounds__(256) void prep2_kernel(
    const float* __restrict__ wvec, short* __restrict__ wfrag)
{
  const int kstep = blockIdx.x;          // 0..31
  const int t = threadIdx.x;
#pragma unroll
  for (int q = 0; q < 4; ++q) {
    const int idx  = t*4 + q;            // 0..1023
    const int c    = idx >> 9;
    const int lane = (idx >> 3) & 63;
    const int e    = idx & 7;
    const int k    = kstep*32 + (lane >> 4)*8 + e;
    const int j    = c*16 + (lane & 15);
    float v = (j < 22) ? wvec[(size_t)j*DD + k] : (j == 22 ? 1.0f : 0.f);
    unsigned u = __float_as_uint(v);
    u = (u + 0x7FFFu + ((u >> 16) & 1u)) >> 16;
    wfrag[(size_t)kstep*1024 + idx] = (short)u;
  }
}

// K1: MFMA dots via wave-private LDS transpose. Block = (n, 64 pos), full K.
// Per wave (owns 16 rows): per 256-k chunk, 16 fully-contiguous 1KB row loads
// -> f32->bf16 -> ds_write_b64 into the wave's private 8KB region (XOR swz)
// -> ds_read_b128 A-frags -> 2 MFMA/ks. Wave-private LDS => in-order DS pipe
// handles RAW/WAR, ZERO barriers in the K loop. B-frags from global (L1-hot,
// same addr across waves). Row-sum rides B's ones-column; ssq from frag regs.
__global__ __launch_bounds__(256, 4) void dots_kernel(
    const float* __restrict__ streams, const short* __restrict__ wfrag,
    float* __restrict__ dots)
{
  __shared__ __align__(16) short tile[16384];  // 32 KB: 4 wave-regions x [16 rows][256 k] bf16

  const int n  = blockIdx.x / 128;
  const int p0 = (blockIdx.x % 128) * 64;
  const int t  = threadIdx.x;
  const int l  = t & 63;
  const int wv = t >> 6;                 // wave 0..3 -> rows [16wv,16wv+16)
  const int lr = l & 15;
  const int g  = l >> 4;                 // 0..3

  short* wreg = tile + wv*4096;          // private 8 KB
  const float* base = streams + ((size_t)(n*RR + p0 + wv*16))*DD;

  f32x4 acc0 = {0.f,0.f,0.f,0.f};
  f32x4 acc1 = {0.f,0.f,0.f,0.f};
  float ssq = 0.f;

  const int rdbase = lr*512 + g*16;      // byte offset pre-swizzle
  const int rdswz  = (lr & 7) << 4;

  for (int chunk = 0; chunk < 4; ++chunk) {
    // ---- stage: 16 rows x 1KB contiguous loads -> bf16 -> private LDS ----
#pragma unroll 4
    for (int r = 0; r < 16; ++r) {
      float4 v = *(const float4*)(base + (size_t)r*DD + chunk*256 + l*4);
      uint2 w2 = make_uint2(bf2(v.x, v.y), bf2(v.z, v.w));
      const int byte = (r*512 + l*8) ^ ((r & 7) << 4);
      *(uint2*)((char*)wreg + byte) = w2;
    }
    // ---- compute: 8 k-steps of 32 ----
#pragma unroll
    for (int ksl = 0; ksl < 8; ++ksl) {
      const int byte = (rdbase + ksl*64) ^ rdswz;
      short8 af = *(const short8*)((char*)wreg + byte);
      const size_t bo = (size_t)(chunk*8 + ksl)*1024 + (size_t)l*8;
      short8 b0 = *(const short8*)(wfrag + bo);
      short8 b1 = *(const short8*)(wfrag + bo + 512);
      acc0 = __builtin_amdgcn_mfma_f32_16x16x32_bf16(af, b0, acc0, 0, 0, 0);
      acc1 = __builtin_amdgcn_mfma_f32_16x16x32_bf16(af, b1, acc1, 0, 0, 0);
#pragma unroll
      for (int e = 0; e < 8; ++e) {
        float xv = __uint_as_float(((unsigned)(unsigned short)af[e]) << 16);
        ssq = fmaf(xv, xv, ssq);
      }
    }
  }

  // ssq: reduce over the 4 g-lanes holding row lr's k-slices
  ssq += __shfl_xor(ssq, 16, 64);
  ssq += __shfl_xor(ssq, 32, 64);

  // ---- epilogue: C (+ sum col 22) + ssq -> fl[64][33], coalesced store ----
  __syncthreads();                        // all waves done with private regions
  float* fl = (float*)tile;
#pragma unroll
  for (int r = 0; r < 4; ++r) {
    fl[(wv*16 + g*4 + r)*33 + lr] = acc0[r];
    if (lr != 7)                          // col 23 reserved for ssq (avoid race)
      fl[(wv*16 + g*4 + r)*33 + 16 + lr] = acc1[r];
  }
  if (l < 16) fl[(wv*16 + lr)*33 + 23] = ssq;
  __syncthreads();
#pragma unroll
  for (int q = 0; q < 6; ++q) {
    const int o   = q*256 + t;            // 0..1535
    const int j   = o >> 6;               // 0..23
    const int row = o & 63;
    dots[((size_t)j*NN + n)*RR + p0 + row] = fl[row*33 + j];
  }
}

// K2: thread per (position, i). Softmax pass-1 weights, pass-2 logit pieces.
__global__ __launch_bounds__(256) void coef_kernel(
    const float* __restrict__ dots, const float* __restrict__ scal,
    float* __restrict__ pack)
{
  const int i = blockIdx.x >> 5;                   // 0..10
  const int p = (blockIdx.x & 31)*256 + threadIdx.x;

  float mu[NN], rs[NN];
#pragma unroll
  for (int n = 0; n < NN; ++n) {
    float s  = dots[((size_t)22*NN + n)*RR + p];
    float q2 = dots[((size_t)23*NN + n)*RR + p];
    mu[n] = s * (1.f/DD);
    rs[n] = rsqrtf(q2*(1.f/DD) - mu[n]*mu[n] + EPSV);
  }

  const float qgA = scal[2*i],        qbA = scal[2*i+1];
  const float qgM = scal[2*(NN+i)],   qbM = scal[2*(NN+i)+1];
  float* pk = pack + (size_t)p*264;

  float w1[NN], dM[NN];
  float mx = -3.0e38f;
#pragma unroll
  for (int n = 0; n < NN; ++n) if (n <= i) {
    float dA = dots[((size_t)i*NN + n)*RR + p];
    dM[n] = dots[((size_t)(NN+i)*NN + n)*RR + p];
    float lg = (dA - mu[n]*qgA)*rs[n] + qbA;
    w1[n] = lg;
    mx = fmaxf(mx, lg);
  }
  float S = 0.f;
#pragma unroll
  for (int n = 0; n < NN; ++n) if (n <= i) { float e = __expf(w1[n]-mx); w1[n] = e; S += e; }
  float inv = 1.f/S;
  float muh = 0.f, hd = 0.f;
#pragma unroll
  for (int n = 0; n < NN; ++n) if (n <= i) {
    w1[n] *= inv;
    muh += w1[n]*mu[n];
    hd  += w1[n]*dM[n];
    pk[i*NN + n] = w1[n];
    if (n < i) pk[121 + i*NN + n] = (dM[n] - mu[n]*qgM)*rs[n] + qbM;
  }
  pk[242 + i] = hd - muh*qgM;
  pk[253 + i] = muh;
}

// K3: one block per position: h sumsq (11 wave reduces), finish logits,
// build C row, combine to out.
__global__ __launch_bounds__(256) void combine_kernel(
    const float* __restrict__ streams,
    const float* __restrict__ pack,
    const float* __restrict__ scal,
    float* __restrict__ out)
{
  __shared__ float P[264];
  __shared__ float red[4][12];
  __shared__ float C[121];

  const int p = blockIdx.x;
  const int t = threadIdx.x;
  const int lane = t & 63, w = t >> 6;

  for (int s = t; s < 264; s += 256) P[s] = pack[(size_t)p*264 + s];

  float4 x[NN];
#pragma unroll
  for (int n = 0; n < NN; ++n)
    x[n] = *(const float4*)(streams + ((size_t)n*RR + p)*DD + 4*t);
  __syncthreads();

  float hss[NN];
#pragma unroll
  for (int i = 0; i < NN; ++i) {
    float4 h = make_float4(0.f,0.f,0.f,0.f);
#pragma unroll
    for (int n = 0; n < NN; ++n) if (n <= i) {
      float wv = P[i*NN + n];
      h.x = fmaf(wv, x[n].x, h.x);
      h.y = fmaf(wv, x[n].y, h.y);
      h.z = fmaf(wv, x[n].z, h.z);
      h.w = fmaf(wv, x[n].w, h.w);
    }
    hss[i] = dot4(h, h);
  }
#pragma unroll
  for (int i = 0; i < NN; ++i) hss[i] = wave_reduce(hss[i]);
  if (lane == 0) {
#pragma unroll
    for (int i = 0; i < NN; ++i) red[w][i] = hss[i];
  }
  __syncthreads();

  if (t < NN) {
    const int i = t;
    float hs   = red[0][i] + red[1][i] + red[2][i] + red[3][i];
    float mu_h = P[253 + i];
    float Ahd  = P[242 + i];
    float varh = hs*(1.f/DD) - mu_h*mu_h;
    float rsh  = rsqrtf(varh + EPSV);
    float qbM  = scal[2*(NN+i)+1];
    float lgh  = Ahd*rsh + qbM;

    float mx2 = lgh;
#pragma unroll
    for (int n = 0; n < NN; ++n) if (n < i) mx2 = fmaxf(mx2, P[121 + i*NN + n]);
    float w2[NN];
    float eh = __expf(lgh - mx2);
    float S2 = eh;
#pragma unroll
    for (int n = 0; n < NN; ++n) if (n < i) {
      float e = __expf(P[121 + i*NN + n] - mx2);
      w2[n] = e;
      S2 += e;
    }
    float inv2 = 1.f/S2;
    float ehw  = eh*inv2;
#pragma unroll
    for (int n = 0; n < NN; ++n) {
      float cc = 0.f;
      if (n < i)  cc = w2[n]*inv2;
      if (n <= i) cc += ehw*P[i*NN + n];
      C[i*NN + n] = cc;
    }
  }
  __syncthreads();

#pragma unroll
  for (int i = 0; i < NN; ++i) {
    float4 o = make_float4(0.f,0.f,0.f,0.f);
#pragma unroll
    for (int n = 0; n < NN; ++n) {
      float cc = C[i*NN + n];
      o.x = fmaf(cc, x[n].x, o.x);
      o.y = fmaf(cc, x[n].y, o.y);
      o.z = fmaf(cc, x[n].z, o.z);
      o.w = fmaf(cc, x[n].w, o.w);
    }
    *(float4*)(out + ((size_t)i*RR + p)*DD + 4*t) = o;
  }
}

extern "C" void kernel_launch(void* const* d_in, const int* in_sizes, int n_in,
                              void* d_out, int out_size, void* d_ws, size_t ws_size,
                              hipStream_t stream) {
  const float* streams = (const float*)d_in[0];
  const float* aq = (const float*)d_in[1];
  const float* ag = (const float*)d_in[2];
  const float* ab = (const float*)d_in[3];
  const float* mq = (const float*)d_in[4];
  const float* mg = (const float*)d_in[5];
  const float* mb = (const float*)d_in[6];
  float* outp = (float*)d_out;

  float* wsf   = (float*)d_ws;
  float* wvec  = wsf;
  float* scal  = wsf + OFF_SCAL;
  short* wfrag = (short*)(wsf + OFF_WFRAG);
  float* dots  = wsf + OFF_DOTS;
  float* pack  = wsf + OFF_PACK;

  prep_kernel<<<dim3(2*NN), dim3(PREP_TPB), 0, stream>>>(aq, ag, ab, mq, mg, mb, wvec, scal);
  prep2_kernel<<<dim3(32), dim3(256), 0, stream>>>(wvec, wfrag);
  dots_kernel<<<dim3(NN*128), dim3(256), 0, stream>>>(streams, wfrag, dots);
  coef_kernel<<<dim3(NN*32), dim3(256), 0, stream>>>(dots, scal, pack);
  combine_kernel<<<dim3(RR), dim3(256), 0, stream>>>(streams, pack, scal, outp);
}

// Round 16
// 259.262 us; speedup vs baseline: 1.0316x; 1.0316x over previous
//
#include <hip/hip_runtime.h>
#include <math.h>

#define NN 11
#define RR 8192               // B*L positions
#define DD 1024
#define EPSV 1e-5f
#define PREP_TPB 256

// ---- ws layout (floats) ----
// wvec  : [22][1024] f32   @ 0
// scal  : [22][2]    f32   @ 22528 (padded to 64)
// wfrag : [32][2][64][8] bf16 @ 22592 (32768 shorts = 16384 float-slots)
// dots  : [24][11][8192]   @ 38976  (j 0..21 dots, 22 sum via ones-col, 23 ssq via Gram)
// pack  : [8192][264]      @ 2201664
#define OFF_SCAL 22528
#define OFF_WFRAG 22592
#define OFF_DOTS 38976
#define OFF_PACK 2201664

typedef __attribute__((ext_vector_type(8))) short short8;
typedef __attribute__((ext_vector_type(4))) float f32x4;

__device__ __forceinline__ float wave_reduce(float v) {
#pragma unroll
  for (int o = 32; o > 0; o >>= 1) v += __shfl_xor(v, o, 64);
  return v;
}

__device__ __forceinline__ float dot4(const float4 a, const float4 b) {
  return a.x*b.x + a.y*b.y + a.z*b.z + a.w*b.w;
}

__device__ __forceinline__ unsigned bf2(float a, float b) {
  unsigned ua = __float_as_uint(a), ub = __float_as_uint(b);
  ua = (ua + 0x7FFFu + ((ua >> 16) & 1u)) >> 16;
  ub = (ub + 0x7FFFu + ((ub >> 16) & 1u)) >> 16;
  return ua | (ub << 16);
}

__device__ __forceinline__ unsigned cvtpk(float lo, float hi) {
  unsigned r;
  asm("v_cvt_pk_bf16_f32 %0, %1, %2" : "=v"(r) : "v"(lo), "v"(hi));
  return r;   // low 16 = bf16(lo), high 16 = bf16(hi); RTNE
}

__global__ __launch_bounds__(PREP_TPB) void prep_kernel(
    const float* __restrict__ aq, const float* __restrict__ ag, const float* __restrict__ ab,
    const float* __restrict__ mq, const float* __restrict__ mg, const float* __restrict__ mb,
    float* __restrict__ wvec, float* __restrict__ scal)
{
  const int j = blockIdx.x;              // 0..21
  const float *q, *g, *bt;
  if (j < NN) { q = aq + (size_t)j*DD;      g = ag + (size_t)j*DD;      bt = ab + (size_t)j*DD; }
  else        { q = mq + (size_t)(j-NN)*DD; g = mg + (size_t)(j-NN)*DD; bt = mb + (size_t)(j-NN)*DD; }
  const int t = threadIdx.x;
  float sqg = 0.f, sqb = 0.f;
  for (int d = t; d < DD; d += PREP_TPB) {
    float qq = q[d];
    float w  = qq * g[d];
    wvec[(size_t)j*DD + d] = w;
    sqg += w;
    sqb += qq * bt[d];
  }
  sqg = wave_reduce(sqg);
  sqb = wave_reduce(sqb);
  __shared__ float red[2][PREP_TPB/64];
  const int lane = t & 63, wid = t >> 6;
  if (lane == 0) { red[0][wid] = sqg; red[1][wid] = sqb; }
  __syncthreads();
  if (t == 0) {
    float a = 0.f, b2 = 0.f;
    for (int w = 0; w < PREP_TPB/64; ++w) { a += red[0][w]; b2 += red[1][w]; }
    scal[2*j]   = a;
    scal[2*j+1] = b2;
  }
}

// pack B fragments: wfrag[kstep][c][lane][e] = bf16(wvec[j][k]), j=c*16+(lane&15),
// k=kstep*32+(lane>>4)*8+e. j==22 -> 1.0 (row-sum rides the MFMA); other j>=22 -> 0.
__global__ __launch_bounds__(256) void prep2_kernel(
    const float* __restrict__ wvec, short* __restrict__ wfrag)
{
  const int kstep = blockIdx.x;          // 0..31
  const int t = threadIdx.x;
#pragma unroll
  for (int q = 0; q < 4; ++q) {
    const int idx  = t*4 + q;            // 0..1023
    const int c    = idx >> 9;
    const int lane = (idx >> 3) & 63;
    const int e    = idx & 7;
    const int k    = kstep*32 + (lane >> 4)*8 + e;
    const int j    = c*16 + (lane & 15);
    float v = (j < 22) ? wvec[(size_t)j*DD + k] : (j == 22 ? 1.0f : 0.f);
    unsigned u = __float_as_uint(v);
    u = (u + 0x7FFFu + ((u >> 16) & 1u)) >> 16;
    wfrag[(size_t)kstep*1024 + idx] = (short)u;
  }
}

// K1: MFMA dots. Block = (n, 64 pos), full K=1024 in 8 chunks of 128.
// Block-cooperative contiguous staging (f32 -> cvt_pk bf16 -> swizzled LDS,
// double-buffered 16KB halves, ONE barrier/chunk, next chunk's loads issued
// before compute = T14). Per ks: 1 ds_read A + 2 global B (L1-hot) + 3 MFMA
// (dots0, dots1+sum-col, Gram for ssq diag). No VALU stats, no shuffles.
__global__ __launch_bounds__(256) void dots_kernel(
    const float* __restrict__ streams, const short* __restrict__ wfrag,
    float* __restrict__ dots)
{
  __shared__ __align__(16) short tile[16384];  // 32 KB: two 16KB halves [64 rows][128 k] bf16

  const int n  = blockIdx.x / 128;
  const int p0 = (blockIdx.x % 128) * 64;
  const int t  = threadIdx.x;
  const int l  = t & 63;
  const int wv = t >> 6;                 // wave 0..3 -> A rows [16wv,16wv+16)
  const int lr = l & 15;
  const int g  = l >> 4;                 // 0..3

  const float* base = streams + ((size_t)(n*RR + p0))*DD;

  // staging geometry: 2048 float4/chunk, 8 per thread; wave-load = 2x512B rows
  int srow[8], scol[8], sbyte[8];
#pragma unroll
  for (int i = 0; i < 8; ++i) {
    const int f4 = i*256 + t;            // 0..2047
    srow[i]  = f4 >> 5;                  // 0..63
    scol[i]  = f4 & 31;
    sbyte[i] = (srow[i]*256 + scol[i]*8) ^ ((srow[i] & 7) << 4);
  }

  f32x4 acc0 = {0.f,0.f,0.f,0.f};        // dots j 0..15
  f32x4 acc1 = {0.f,0.f,0.f,0.f};        // dots j 16..21 + sum col 22
  f32x4 acc2 = {0.f,0.f,0.f,0.f};        // Gram (diag = ssq)

  const int arow   = wv*16 + lr;
  const int arbase = arow*256;           // + ks*64 + g*16, then XOR
  const int arswz  = (arow & 7) << 4;

  float4 st[8];
  // ---- prologue: stage chunk 0 into half 0 ----
#pragma unroll
  for (int i = 0; i < 8; ++i)
    st[i] = *(const float4*)(base + (size_t)srow[i]*DD + scol[i]*4);
#pragma unroll
  for (int i = 0; i < 8; ++i)
    *(uint2*)((char*)tile + sbyte[i]) =
        make_uint2(cvtpk(st[i].x, st[i].y), cvtpk(st[i].z, st[i].w));
  __syncthreads();

  for (int chunk = 0; chunk < 8; ++chunk) {
    short* curh = tile + ((chunk & 1) ? 8192 : 0);
    short* nxth = tile + ((chunk & 1) ? 0 : 8192);

    // ---- issue next chunk's loads (in flight across compute + barrier) ----
    if (chunk < 7) {
#pragma unroll
      for (int i = 0; i < 8; ++i)
        st[i] = *(const float4*)(base + (size_t)srow[i]*DD + (chunk+1)*128 + scol[i]*4);
    }

    // ---- compute: 4 k-steps of 32 from current half ----
#pragma unroll
    for (int ksl = 0; ksl < 4; ++ksl) {
      const int byte = (arbase + ksl*64 + g*16) ^ arswz;
      short8 af = *(const short8*)((char*)curh + byte);
      const size_t bo = (size_t)(chunk*4 + ksl)*1024 + (size_t)l*8;
      short8 b0 = *(const short8*)(wfrag + bo);
      short8 b1 = *(const short8*)(wfrag + bo + 512);
      acc0 = __builtin_amdgcn_mfma_f32_16x16x32_bf16(af, b0, acc0, 0, 0, 0);
      acc1 = __builtin_amdgcn_mfma_f32_16x16x32_bf16(af, b1, acc1, 0, 0, 0);
      acc2 = __builtin_amdgcn_mfma_f32_16x16x32_bf16(af, af, acc2, 0, 0, 0);
    }

    // ---- commit staged data to the other half; one barrier per chunk ----
    if (chunk < 7) {
#pragma unroll
      for (int i = 0; i < 8; ++i)
        *(uint2*)((char*)nxth + sbyte[i]) =
            make_uint2(cvtpk(st[i].x, st[i].y), cvtpk(st[i].z, st[i].w));
      __syncthreads();
    }
  }

  // ---- epilogue: C tiles + stats -> fl[64][33], coalesced store ----
  __syncthreads();                        // all waves done reading LDS halves
  float* fl = (float*)tile;
#pragma unroll
  for (int r = 0; r < 4; ++r) {
    fl[(wv*16 + g*4 + r)*33 + lr] = acc0[r];
    if (lr != 7)                          // col 23 reserved for ssq
      fl[(wv*16 + g*4 + r)*33 + 16 + lr] = acc1[r];
  }
  // ssq from Gram diagonal: D[row][col], row=(g*4+r), col=lr; diag row==col
#pragma unroll
  for (int r = 0; r < 4; ++r) {
    if (g*4 + r == lr)
      fl[(wv*16 + lr)*33 + 23] = acc2[r];
  }
  __syncthreads();
#pragma unroll
  for (int q = 0; q < 6; ++q) {
    const int o   = q*256 + t;            // 0..1535
    const int j   = o >> 6;               // 0..23
    const int row = o & 63;
    dots[((size_t)j*NN + n)*RR + p0 + row] = fl[row*33 + j];
  }
}

// K2: thread per (position, i). Softmax pass-1 weights, pass-2 logit pieces.
__global__ __launch_bounds__(256) void coef_kernel(
    const float* __restrict__ dots, const float* __restrict__ scal,
    float* __restrict__ pack)
{
  const int i = blockIdx.x >> 5;                   // 0..10
  const int p = (blockIdx.x & 31)*256 + threadIdx.x;

  float mu[NN], rs[NN];
#pragma unroll
  for (int n = 0; n < NN; ++n) {
    float s  = dots[((size_t)22*NN + n)*RR + p];
    float q2 = dots[((size_t)23*NN + n)*RR + p];
    mu[n] = s * (1.f/DD);
    rs[n] = rsqrtf(q2*(1.f/DD) - mu[n]*mu[n] + EPSV);
  }

  const float qgA = scal[2*i],        qbA = scal[2*i+1];
  const float qgM = scal[2*(NN+i)],   qbM = scal[2*(NN+i)+1];
  float* pk = pack + (size_t)p*264;

  float w1[NN], dM[NN];
  float mx = -3.0e38f;
#pragma unroll
  for (int n = 0; n < NN; ++n) if (n <= i) {
    float dA = dots[((size_t)i*NN + n)*RR + p];
    dM[n] = dots[((size_t)(NN+i)*NN + n)*RR + p];
    float lg = (dA - mu[n]*qgA)*rs[n] + qbA;
    w1[n] = lg;
    mx = fmaxf(mx, lg);
  }
  float S = 0.f;
#pragma unroll
  for (int n = 0; n < NN; ++n) if (n <= i) { float e = __expf(w1[n]-mx); w1[n] = e; S += e; }
  float inv = 1.f/S;
  float muh = 0.f, hd = 0.f;
#pragma unroll
  for (int n = 0; n < NN; ++n) if (n <= i) {
    w1[n] *= inv;
    muh += w1[n]*mu[n];
    hd  += w1[n]*dM[n];
    pk[i*NN + n] = w1[n];
    if (n < i) pk[121 + i*NN + n] = (dM[n] - mu[n]*qgM)*rs[n] + qbM;
  }
  pk[242 + i] = hd - muh*qgM;
  pk[253 + i] = muh;
}

// K3: one block per position: h sumsq (11 wave reduces), finish logits,
// build C row, combine to out.
__global__ __launch_bounds__(256) void combine_kernel(
    const float* __restrict__ streams,
    const float* __restrict__ pack,
    const float* __restrict__ scal,
    float* __restrict__ out)
{
  __shared__ float P[264];
  __shared__ float red[4][12];
  __shared__ float C[121];

  const int p = blockIdx.x;
  const int t = threadIdx.x;
  const int lane = t & 63, w = t >> 6;

  for (int s = t; s < 264; s += 256) P[s] = pack[(size_t)p*264 + s];

  float4 x[NN];
#pragma unroll
  for (int n = 0; n < NN; ++n)
    x[n] = *(const float4*)(streams + ((size_t)n*RR + p)*DD + 4*t);
  __syncthreads();

  float hss[NN];
#pragma unroll
  for (int i = 0; i < NN; ++i) {
    float4 h = make_float4(0.f,0.f,0.f,0.f);
#pragma unroll
    for (int n = 0; n < NN; ++n) if (n <= i) {
      float wv = P[i*NN + n];
      h.x = fmaf(wv, x[n].x, h.x);
      h.y = fmaf(wv, x[n].y, h.y);
      h.z = fmaf(wv, x[n].z, h.z);
      h.w = fmaf(wv, x[n].w, h.w);
    }
    hss[i] = dot4(h, h);
  }
#pragma unroll
  for (int i = 0; i < NN; ++i) hss[i] = wave_reduce(hss[i]);
  if (lane == 0) {
#pragma unroll
    for (int i = 0; i < NN; ++i) red[w][i] = hss[i];
  }
  __syncthreads();

  if (t < NN) {
    const int i = t;
    float hs   = red[0][i] + red[1][i] + red[2][i] + red[3][i];
    float mu_h = P[253 + i];
    float Ahd  = P[242 + i];
    float varh = hs*(1.f/DD) - mu_h*mu_h;
    float rsh  = rsqrtf(varh + EPSV);
    float qbM  = scal[2*(NN+i)+1];
    float lgh  = Ahd*rsh + qbM;

    float mx2 = lgh;
#pragma unroll
    for (int n = 0; n < NN; ++n) if (n < i) mx2 = fmaxf(mx2, P[121 + i*NN + n]);
    float w2[NN];
    float eh = __expf(lgh - mx2);
    float S2 = eh;
#pragma unroll
    for (int n = 0; n < NN; ++n) if (n < i) {
      float e = __expf(P[121 + i*NN + n] - mx2);
      w2[n] = e;
      S2 += e;
    }
    float inv2 = 1.f/S2;
    float ehw  = eh*inv2;
#pragma unroll
    for (int n = 0; n < NN; ++n) {
      float cc = 0.f;
      if (n < i)  cc = w2[n]*inv2;
      if (n <= i) cc += ehw*P[i*NN + n];
      C[i*NN + n] = cc;
    }
  }
  __syncthreads();

#pragma unroll
  for (int i = 0; i < NN; ++i) {
    float4 o = make_float4(0.f,0.f,0.f,0.f);
#pragma unroll
    for (int n = 0; n < NN; ++n) {
      float cc = C[i*NN + n];
      o.x = fmaf(cc, x[n].x, o.x);
      o.y = fmaf(cc, x[n].y, o.y);
      o.z = fmaf(cc, x[n].z, o.z);
      o.w = fmaf(cc, x[n].w, o.w);
    }
    *(float4*)(out + ((size_t)i*RR + p)*DD + 4*t) = o;
  }
}

extern "C" void kernel_launch(void* const* d_in, const int* in_sizes, int n_in,
                              void* d_out, int out_size, void* d_ws, size_t ws_size,
                              hipStream_t stream) {
  const float* streams = (const float*)d_in[0];
  const float* aq = (const float*)d_in[1];
  const float* ag = (const float*)d_in[2];
  const float* ab = (const float*)d_in[3];
  const float* mq = (const float*)d_in[4];
  const float* mg = (const float*)d_in[5];
  const float* mb = (const float*)d_in[6];
  float* outp = (float*)d_out;

  float* wsf   = (float*)d_ws;
  float* wvec  = wsf;
  float* scal  = wsf + OFF_SCAL;
  short* wfrag = (short*)(wsf + OFF_WFRAG);
  float* dots  = wsf + OFF_DOTS;
  float* pack  = wsf + OFF_PACK;

  prep_kernel<<<dim3(2*NN), dim3(PREP_TPB), 0, stream>>>(aq, ag, ab, mq, mg, mb, wvec, scal);
  prep2_kernel<<<dim3(32), dim3(256), 0, stream>>>(wvec, wfrag);
  dots_kernel<<<dim3(NN*128), dim3(256), 0, stream>>>(streams, wfrag, dots);
  coef_kernel<<<dim3(NN*32), dim3(256), 0, stream>>>(dots, scal, pack);
  combine_kernel<<<dim3(RR), dim3(256), 0, stream>>>(streams, pack, scal, outp);
}

// Round 17
// 246.328 us; speedup vs baseline: 1.0858x; 1.0525x over previous
//
#include <hip/hip_runtime.h>
#include <math.h>

#define NN 11
#define RR 8192               // B*L positions
#define DD 1024
#define EPSV 1e-5f
#define PREP_TPB 256

// ---- ws layout (floats) ----
// wvec  : [22][1024] f32   @ 0
// scal  : [22][2]    f32   @ 22528 (padded to 64)
// wfrag : [32][2][64][8] bf16 @ 22592 (32768 shorts = 16384 float-slots)
#define OFF_SCAL 22528
#define OFF_WFRAG 22592

typedef __attribute__((ext_vector_type(8))) short short8;
typedef __attribute__((ext_vector_type(4))) float f32x4;

__device__ __forceinline__ float wave_reduce(float v) {
#pragma unroll
  for (int o = 32; o > 0; o >>= 1) v += __shfl_xor(v, o, 64);
  return v;
}

__device__ __forceinline__ unsigned cvtpk(float lo, float hi) {
  unsigned r;
  asm("v_cvt_pk_bf16_f32 %0, %1, %2" : "=v"(r) : "v"(lo), "v"(hi));
  return r;   // low16=bf16(lo), high16=bf16(hi); RTNE
}

__device__ __forceinline__ float b2f(short s) {
  return __uint_as_float(((unsigned)(unsigned short)s) << 16);
}

__global__ __launch_bounds__(PREP_TPB) void prep_kernel(
    const float* __restrict__ aq, const float* __restrict__ ag, const float* __restrict__ ab,
    const float* __restrict__ mq, const float* __restrict__ mg, const float* __restrict__ mb,
    float* __restrict__ wvec, float* __restrict__ scal)
{
  const int j = blockIdx.x;              // 0..21
  const float *q, *g, *bt;
  if (j < NN) { q = aq + (size_t)j*DD;      g = ag + (size_t)j*DD;      bt = ab + (size_t)j*DD; }
  else        { q = mq + (size_t)(j-NN)*DD; g = mg + (size_t)(j-NN)*DD; bt = mb + (size_t)(j-NN)*DD; }
  const int t = threadIdx.x;
  float sqg = 0.f, sqb = 0.f;
  for (int d = t; d < DD; d += PREP_TPB) {
    float qq = q[d];
    float w  = qq * g[d];
    wvec[(size_t)j*DD + d] = w;
    sqg += w;
    sqb += qq * bt[d];
  }
  sqg = wave_reduce(sqg);
  sqb = wave_reduce(sqb);
  __shared__ float red[2][PREP_TPB/64];
  const int lane = t & 63, wid = t >> 6;
  if (lane == 0) { red[0][wid] = sqg; red[1][wid] = sqb; }
  __syncthreads();
  if (t == 0) {
    float a = 0.f, b2 = 0.f;
    for (int w = 0; w < PREP_TPB/64; ++w) { a += red[0][w]; b2 += red[1][w]; }
    scal[2*j]   = a;
    scal[2*j+1] = b2;
  }
}

// pack B fragments: wfrag[kstep][c][lane][e] = bf16(wvec[j][k]), j=c*16+(lane&15),
// k=kstep*32+(lane>>4)*8+e. j==22 -> 1.0 (row-sum rides the MFMA); other j>=22 -> 0.
__global__ __launch_bounds__(256) void prep2_kernel(
    const float* __restrict__ wvec, short* __restrict__ wfrag)
{
  const int kstep = blockIdx.x;          // 0..31
  const int t = threadIdx.x;
#pragma unroll
  for (int q = 0; q < 4; ++q) {
    const int idx  = t*4 + q;            // 0..1023
    const int c    = idx >> 9;
    const int lane = (idx >> 3) & 63;
    const int e    = idx & 7;
    const int k    = kstep*32 + (lane >> 4)*8 + e;
    const int j    = c*16 + (lane & 15);
    float v = (j < 22) ? wvec[(size_t)j*DD + k] : (j == 22 ? 1.0f : 0.f);
    unsigned u = __float_as_uint(v);
    u = (u + 0x7FFFu + ((u >> 16) & 1u)) >> 16;
    wfrag[(size_t)kstep*1024 + idx] = (short)u;
  }
}

// Fused kernel: block = 2 positions. Streams read from HBM ONCE.
// Phases: stage(f32->bf16 LDS tile) -> MFMA dots(+sum ones-col, +ssq Gram
// diag) -> coef1 (w1, lg2, Ahd) -> h-sumsq from tile -> coef2 (C, zero-pad)
// -> final weighted sum -> coalesced f32 stores.
__global__ __launch_bounds__(256) void fused_kernel(
    const float* __restrict__ streams, const short* __restrict__ wfrag,
    const float* __restrict__ scal, float* __restrict__ out)
{
  __shared__ __align__(16) short xt[22*1024];    // 45056 B, swizzled bf16 tile
  __shared__ float fl[24][33];                   // dots scratch
  __shared__ float murs[22][2];                  // mu, rsig per (pos,n)
  __shared__ float w1s[22][11];                  // pass-1 weights (zero-padded)
  __shared__ float lg2s[22][11];                 // pass-2 logits
  __shared__ float msc[22][2];                   // muh, Ahd
  __shared__ float Cs[22][11];                   // final coeffs (zero-padded)
  __shared__ float hred[4][11];                  // per-wave h-sumsq partials

  const int p0 = blockIdx.x * 2;
  const int t  = threadIdx.x;
  const int l  = t & 63;
  const int wv = t >> 6;

  // ---- STAGE: 22 rows x 1024 f32 -> bf16 LDS; one float4/thread/row ----
#pragma unroll
  for (int i = 0; i < 22; ++i) {
    const int pos = i / 11, n = i % 11;
    float4 v = *(const float4*)(streams + ((size_t)(n*RR + p0 + pos))*DD + t*4);
    const int byte = (i*2048 + t*8) ^ ((i & 7) << 4);
    *(uint2*)((char*)xt + byte) = make_uint2(cvtpk(v.x, v.y), cvtpk(v.z, v.w));
  }
  __syncthreads();

  // ---- MFMA dots: 4 waves = (row-half rh) x (K-half kh) ----
  const int rh = wv & 1, kh = wv >> 1;
  const int lr = l & 15, g = l >> 4;
  int arow = rh*16 + lr; if (arow > 21) arow = 21;   // clamp pad rows (discarded)
  const int abase = arow*2048;
  const int aswz  = (arow & 7) << 4;

  f32x4 acc0 = {0.f,0.f,0.f,0.f};        // dots j 0..15
  f32x4 acc1 = {0.f,0.f,0.f,0.f};        // dots 16..21 + sum col 22
  f32x4 acc2 = {0.f,0.f,0.f,0.f};        // Gram (diag = ssq)
#pragma unroll
  for (int ks = 0; ks < 16; ++ks) {
    const int kbyte = (kh*512 + ks*32 + g*8) * 2;
    short8 af = *(const short8*)((char*)xt + ((abase + kbyte) ^ aswz));
    const size_t bo = (size_t)(kh*16 + ks)*1024 + (size_t)l*8;
    short8 b0 = *(const short8*)(wfrag + bo);
    short8 b1 = *(const short8*)(wfrag + bo + 512);
    acc0 = __builtin_amdgcn_mfma_f32_16x16x32_bf16(af, b0, acc0, 0, 0, 0);
    acc1 = __builtin_amdgcn_mfma_f32_16x16x32_bf16(af, b1, acc1, 0, 0, 0);
    acc2 = __builtin_amdgcn_mfma_f32_16x16x32_bf16(af, af, acc2, 0, 0, 0);
  }
  if (kh == 1) {                          // phase A: kh=1 waves write
#pragma unroll
    for (int r = 0; r < 4; ++r) {
      const int row = rh*16 + g*4 + r;
      if (row < 22) {
        fl[row][lr] = acc0[r];
        if (lr != 7) fl[row][16+lr] = acc1[r];
        if (g*4+r == lr) fl[row][23] = acc2[r];
      }
    }
  }
  __syncthreads();
  if (kh == 0) {                          // phase B: kh=0 waves accumulate
#pragma unroll
    for (int r = 0; r < 4; ++r) {
      const int row = rh*16 + g*4 + r;
      if (row < 22) {
        fl[row][lr] += acc0[r];
        if (lr != 7) fl[row][16+lr] += acc1[r];
        if (g*4+r == lr) fl[row][23] += acc2[r];
      }
    }
  }
  __syncthreads();

  // ---- stats per row ----
  if (t < 22) {
    float mu = fl[t][22] * (1.f/DD);
    float vr = fl[t][23] * (1.f/DD) - mu*mu;
    murs[t][0] = mu;
    murs[t][1] = rsqrtf(vr + EPSV);
  }
  __syncthreads();

  // ---- coef part 1: thread (pos,i) -> w1 (zero-padded), lg2, muh, Ahd ----
  if (t < 22) {
    const int pos = t / 11, i = t % 11;
    const float qgA = scal[2*i],      qbA = scal[2*i+1];
    const float qgM = scal[2*(NN+i)], qbM = scal[2*(NN+i)+1];
    float w1[NN];
    float mx = -3.0e38f;
#pragma unroll
    for (int n = 0; n < NN; ++n) if (n <= i) {
      const int row = pos*11 + n;
      float lg = (fl[row][n <= i ? i : 0] - murs[row][0]*qgA)*murs[row][1] + qbA;
      w1[n] = lg;
      mx = fmaxf(mx, lg);
    }
    float S = 0.f;
#pragma unroll
    for (int n = 0; n < NN; ++n) if (n <= i) { float e = __expf(w1[n]-mx); w1[n] = e; S += e; }
    const float inv = 1.f/S;
    float muh = 0.f, hd = 0.f;
#pragma unroll
    for (int n = 0; n < NN; ++n) {
      if (n <= i) {
        w1[n] *= inv;
        const int row = pos*11 + n;
        muh += w1[n]*murs[row][0];
        hd  += w1[n]*fl[row][11+i];
        w1s[t][n]  = w1[n];
        lg2s[t][n] = (n < i) ? (fl[row][11+i] - murs[row][0]*qgM)*murs[row][1] + qbM : 0.f;
      } else {
        w1s[t][n] = 0.f;
        lg2s[t][n] = 0.f;
      }
    }
    msc[t][0] = muh;
    msc[t][1] = hd - muh*qgM;
  }
  __syncthreads();

  // ---- load this thread's x slice (pos, 8 k's, 11 n) and convert ----
  const int pos = t >> 7;
  const int kt  = (t & 127) * 8;
  float xf[11][8];
#pragma unroll
  for (int n = 0; n < 11; ++n) {
    const int row = pos*11 + n;
    short8 xs = *(const short8*)((char*)xt + ((row*2048 + kt*2) ^ ((row & 7) << 4)));
#pragma unroll
    for (int e = 0; e < 8; ++e) xf[n][e] = b2f(xs[e]);
  }

  // ---- h-sumsq pass ----
  float hss[11];
#pragma unroll
  for (int i = 0; i < 11; ++i) {
    float h[8] = {0.f,0.f,0.f,0.f,0.f,0.f,0.f,0.f};
    const float* wr = w1s[pos*11 + i];
#pragma unroll
    for (int n = 0; n < 11; ++n) {
      const float w = wr[n];
#pragma unroll
      for (int e = 0; e < 8; ++e) h[e] = fmaf(w, xf[n][e], h[e]);
    }
    float s = 0.f;
#pragma unroll
    for (int e = 0; e < 8; ++e) s = fmaf(h[e], h[e], s);
    hss[i] = s;
  }
#pragma unroll
  for (int i = 0; i < 11; ++i) hss[i] = wave_reduce(hss[i]);
  if (l == 0) {
#pragma unroll
    for (int i = 0; i < 11; ++i) hred[wv][i] = hss[i];
  }
  __syncthreads();

  // ---- coef part 2: lgh, w2, final C (zero-padded) ----
  if (t < 22) {
    const int pos2 = t / 11, i = t % 11;
    const float hs   = hred[2*pos2][i] + hred[2*pos2+1][i];
    const float muh  = msc[t][0];
    const float Ahd  = msc[t][1];
    const float varh = hs*(1.f/DD) - muh*muh;
    const float rsh  = rsqrtf(varh + EPSV);
    const float qbM  = scal[2*(NN+i)+1];
    const float lgh  = Ahd*rsh + qbM;

    float mx2 = lgh;
#pragma unroll
    for (int n = 0; n < NN; ++n) if (n < i) mx2 = fmaxf(mx2, lg2s[t][n]);
    float w2[NN];
    float eh = __expf(lgh - mx2);
    float S2 = eh;
#pragma unroll
    for (int n = 0; n < NN; ++n) if (n < i) {
      float e = __expf(lg2s[t][n] - mx2);
      w2[n] = e;
      S2 += e;
    }
    const float inv2 = 1.f/S2;
    const float ehw  = eh*inv2;
#pragma unroll
    for (int n = 0; n < NN; ++n) {
      float cc = ehw * w1s[t][n];          // w1s zero-padded for n>i
      if (n < i) cc += w2[n]*inv2;
      Cs[t][n] = cc;
    }
  }
  __syncthreads();

  // ---- final combine: branchless over n (Cs zero-padded), coalesced store ----
#pragma unroll
  for (int i = 0; i < 11; ++i) {
    float o[8] = {0.f,0.f,0.f,0.f,0.f,0.f,0.f,0.f};
    const float* Crow = Cs[pos*11 + i];
#pragma unroll
    for (int n = 0; n < 11; ++n) {
      const float c = Crow[n];
#pragma unroll
      for (int e = 0; e < 8; ++e) o[e] = fmaf(c, xf[n][e], o[e]);
    }
    float* dst = out + ((size_t)(i*RR + p0 + pos))*DD + kt;
    *(float4*)dst       = make_float4(o[0], o[1], o[2], o[3]);
    *(float4*)(dst + 4) = make_float4(o[4], o[5], o[6], o[7]);
  }
}

extern "C" void kernel_launch(void* const* d_in, const int* in_sizes, int n_in,
                              void* d_out, int out_size, void* d_ws, size_t ws_size,
                              hipStream_t stream) {
  const float* streams = (const float*)d_in[0];
  const float* aq = (const float*)d_in[1];
  const float* ag = (const float*)d_in[2];
  const float* ab = (const float*)d_in[3];
  const float* mq = (const float*)d_in[4];
  const float* mg = (const float*)d_in[5];
  const float* mb = (const float*)d_in[6];
  float* outp = (float*)d_out;

  float* wsf   = (float*)d_ws;
  float* wvec  = wsf;
  float* scal  = wsf + OFF_SCAL;
  short* wfrag = (short*)(wsf + OFF_WFRAG);

  prep_kernel<<<dim3(2*NN), dim3(PREP_TPB), 0, stream>>>(aq, ag, ab, mq, mg, mb, wvec, scal);
  prep2_kernel<<<dim3(32), dim3(256), 0, stream>>>(wvec, wfrag);
  fused_kernel<<<dim3(RR/2), dim3(256), 0, stream>>>(streams, wfrag, scal, outp);
}

// Round 18
// 191.743 us; speedup vs baseline: 1.3949x; 1.2847x over previous
//
#include <hip/hip_runtime.h>
#include <math.h>

#define NN 11
#define RR 8192               // B*L positions
#define DD 1024
#define EPSV 1e-5f
#define PREP_TPB 256

// ---- ws layout (floats) ----
// wvec  : [22][1024] f32   @ 0
// scal  : [22][2]    f32   @ 22528 (padded to 64)
// wfrag : [32][2][64][8] bf16 @ 22592
#define OFF_SCAL 22528
#define OFF_WFRAG 22592

typedef __attribute__((ext_vector_type(8))) short short8;
typedef __attribute__((ext_vector_type(4))) float f32x4;

__device__ __forceinline__ float wave_reduce(float v) {
#pragma unroll
  for (int o = 32; o > 0; o >>= 1) v += __shfl_xor(v, o, 64);
  return v;
}

__device__ __forceinline__ unsigned cvtpk(float lo, float hi) {
  unsigned r;
  asm("v_cvt_pk_bf16_f32 %0, %1, %2" : "=v"(r) : "v"(lo), "v"(hi));
  return r;   // low16=bf16(lo), high16=bf16(hi); RTNE
}

__device__ __forceinline__ float b2f(unsigned short s) {
  return __uint_as_float(((unsigned)s) << 16);
}

__global__ __launch_bounds__(PREP_TPB) void prep_kernel(
    const float* __restrict__ aq, const float* __restrict__ ag, const float* __restrict__ ab,
    const float* __restrict__ mq, const float* __restrict__ mg, const float* __restrict__ mb,
    float* __restrict__ wvec, float* __restrict__ scal)
{
  const int j = blockIdx.x;              // 0..21
  const float *q, *g, *bt;
  if (j < NN) { q = aq + (size_t)j*DD;      g = ag + (size_t)j*DD;      bt = ab + (size_t)j*DD; }
  else        { q = mq + (size_t)(j-NN)*DD; g = mg + (size_t)(j-NN)*DD; bt = mb + (size_t)(j-NN)*DD; }
  const int t = threadIdx.x;
  float sqg = 0.f, sqb = 0.f;
  for (int d = t; d < DD; d += PREP_TPB) {
    float qq = q[d];
    float w  = qq * g[d];
    wvec[(size_t)j*DD + d] = w;
    sqg += w;
    sqb += qq * bt[d];
  }
  sqg = wave_reduce(sqg);
  sqb = wave_reduce(sqb);
  __shared__ float red[2][PREP_TPB/64];
  const int lane = t & 63, wid = t >> 6;
  if (lane == 0) { red[0][wid] = sqg; red[1][wid] = sqb; }
  __syncthreads();
  if (t == 0) {
    float a = 0.f, b2 = 0.f;
    for (int w = 0; w < PREP_TPB/64; ++w) { a += red[0][w]; b2 += red[1][w]; }
    scal[2*j]   = a;
    scal[2*j+1] = b2;
  }
}

// pack B fragments: wfrag[kstep][c][lane][e] = bf16(wvec[j][k]), j=c*16+(lane&15),
// k=kstep*32+(lane>>4)*8+e. j==22 -> 1.0 (row-sum rides the MFMA); other j>=22 -> 0.
__global__ __launch_bounds__(256) void prep2_kernel(
    const float* __restrict__ wvec, short* __restrict__ wfrag)
{
  const int kstep = blockIdx.x;          // 0..31
  const int t = threadIdx.x;
#pragma unroll
  for (int q = 0; q < 4; ++q) {
    const int idx  = t*4 + q;            // 0..1023
    const int c    = idx >> 9;
    const int lane = (idx >> 3) & 63;
    const int e    = idx & 7;
    const int k    = kstep*32 + (lane >> 4)*8 + e;
    const int j    = c*16 + (lane & 15);
    float v = (j < 22) ? wvec[(size_t)j*DD + k] : (j == 22 ? 1.0f : 0.f);
    unsigned u = __float_as_uint(v);
    u = (u + 0x7FFFu + ((u >> 16) & 1u)) >> 16;
    wfrag[(size_t)kstep*1024 + idx] = (short)u;
  }
}

// Fused: block = ONE position. Streams read once. Phases:
// stage(11 rows f32->bf16 LDS) -> MFMA (4 waves split K, per-wave partial
// regions: dots 0..15 / 16..22(sum) / Gram 11 cols) -> 2-iter reduce ->
// single t<11 scalar phase (stats + w1 + hss=w1'Gw1 + w2 -> C) ->
// combine (xf[11][4]) + coalesced stores. 5 barriers, ~29.5 KB LDS.
__global__ __launch_bounds__(256) void fused_kernel(
    const float* __restrict__ streams, const short* __restrict__ wfrag,
    const float* __restrict__ scal, float* __restrict__ out)
{
  __shared__ __align__(16) short xt[NN*1024];    // 22528 B bf16 tile, swizzled
  __shared__ float fl4[4*11*40];                 // per-wave partials; reduced into [0]
  __shared__ float Cs[11][12];                   // final coeffs (zero-padded)

  const int p  = blockIdx.x;
  const int t  = threadIdx.x;
  const int l  = t & 63;
  const int wv = t >> 6;

  // ---- STAGE: 11 rows x 1024 f32 -> bf16 LDS; one float4/thread/row ----
#pragma unroll
  for (int n = 0; n < NN; ++n) {
    float4 v = *(const float4*)(streams + ((size_t)(n*RR + p))*DD + t*4);
    const int byte = (n*2048 + t*8) ^ ((n & 7) << 4);
    *(uint2*)((char*)xt + byte) = make_uint2(cvtpk(v.x, v.y), cvtpk(v.z, v.w));
  }
  __syncthreads();

  // ---- MFMA: wave wv handles ksteps [wv*8, wv*8+8) ----
  const int lr = l & 15, g = l >> 4;
  const int arow  = (lr < NN) ? lr : (NN-1);     // clamp pad rows (discarded)
  const int abase = arow*2048;
  const int aswz  = (arow & 7) << 4;

  f32x4 acc0 = {0.f,0.f,0.f,0.f};        // dots j 0..15
  f32x4 acc1 = {0.f,0.f,0.f,0.f};        // dots j 16..21 + sum col 22
  f32x4 acc2 = {0.f,0.f,0.f,0.f};        // Gram
#pragma unroll
  for (int ksl = 0; ksl < 8; ++ksl) {
    const int ks = wv*8 + ksl;
    const int byte = (abase + ks*64 + g*16) ^ aswz;
    short8 af = *(const short8*)((char*)xt + byte);
    const size_t bo = (size_t)ks*1024 + (size_t)l*8;
    short8 b0 = *(const short8*)(wfrag + bo);
    short8 b1 = *(const short8*)(wfrag + bo + 512);
    acc0 = __builtin_amdgcn_mfma_f32_16x16x32_bf16(af, b0, acc0, 0, 0, 0);
    acc1 = __builtin_amdgcn_mfma_f32_16x16x32_bf16(af, b1, acc1, 0, 0, 0);
    acc2 = __builtin_amdgcn_mfma_f32_16x16x32_bf16(af, af, acc2, 0, 0, 0);
  }
  // per-wave partial region [11][40]: 0..15 dots, 16..22 dots+sum, 24..34 Gram
  {
    float* R0 = fl4 + wv*440;
#pragma unroll
    for (int r = 0; r < 4; ++r) {
      const int row = g*4 + r;
      if (row < NN) {
        float* R = R0 + row*40;
        R[lr] = acc0[r];
        if (lr <= 6)  R[16 + lr] = acc1[r];
        if (lr < NN)  R[24 + lr] = acc2[r];
      }
    }
  }
  __syncthreads();

  // ---- reduce the 4 wave partials into fl4[0] (440 entries) ----
  for (int s = t; s < 440; s += 256)
    fl4[s] = fl4[s] + fl4[440 + s] + fl4[880 + s] + fl4[1320 + s];
  __syncthreads();

  // ---- single scalar phase: thread i<11 computes its full C row ----
  if (t < NN) {
    const int i = t;
    const float qgA = scal[2*i],      qbA = scal[2*i+1];
    const float qgM = scal[2*(NN+i)], qbM = scal[2*(NN+i)+1];

    float mu[NN], rs[NN];
#pragma unroll
    for (int n = 0; n < NN; ++n) {
      mu[n] = fl4[n*40 + 22] * (1.f/DD);
      float vr = fl4[n*40 + 24 + n] * (1.f/DD) - mu[n]*mu[n];
      rs[n] = rsqrtf(vr + EPSV);
    }

    float w1[NN], dM[NN];
    float mx = -3.0e38f;
#pragma unroll
    for (int n = 0; n < NN; ++n) {
      w1[n] = 0.f;
      if (n <= i) {
        float lg = (fl4[n*40 + i] - mu[n]*qgA)*rs[n] + qbA;
        w1[n] = lg;
        mx = fmaxf(mx, lg);
      }
    }
    float S = 0.f;
#pragma unroll
    for (int n = 0; n < NN; ++n) if (n <= i) { float e = __expf(w1[n]-mx); w1[n] = e; S += e; }
    const float inv = 1.f/S;
    float muh = 0.f, hd = 0.f;
#pragma unroll
    for (int n = 0; n < NN; ++n) {
      if (n <= i) {
        w1[n] *= inv;
        dM[n] = fl4[n*40 + 11 + i];
        muh += w1[n]*mu[n];
        hd  += w1[n]*dM[n];
      } else w1[n] = 0.f;
    }

    // hss = w1' G w1 via the MFMA Gram (zero-padded w1 -> branchless)
    float hss = 0.f;
#pragma unroll
    for (int m = 0; m < NN; ++m) {
      const float wm = w1[m];
      float acc = 0.f;
#pragma unroll
      for (int n = 0; n < NN; ++n) acc = fmaf(w1[n], fl4[m*40 + 24 + n], acc);
      hss = fmaf(wm, acc, hss);
    }
    const float varh = hss*(1.f/DD) - muh*muh;
    const float rsh  = rsqrtf(varh + EPSV);
    const float lgh  = (hd - muh*qgM)*rsh + qbM;

    float lg2[NN], w2[NN];
    float mx2 = lgh;
#pragma unroll
    for (int n = 0; n < NN; ++n) if (n < i) {
      lg2[n] = (dM[n] - mu[n]*qgM)*rs[n] + qbM;
      mx2 = fmaxf(mx2, lg2[n]);
    }
    float eh = __expf(lgh - mx2);
    float S2 = eh;
#pragma unroll
    for (int n = 0; n < NN; ++n) if (n < i) { w2[n] = __expf(lg2[n]-mx2); S2 += w2[n]; }
    const float inv2 = 1.f/S2;
    const float ehw  = eh*inv2;
#pragma unroll
    for (int n = 0; n < NN; ++n) {
      float cc = ehw * w1[n];              // w1 zero-padded for n>i
      if (n < i) cc += w2[n]*inv2;
      Cs[i][n] = cc;
    }
  }
  __syncthreads();

  // ---- combine: thread owns 4 k's; branchless over n; coalesced stores ----
  const int kt = t*4;
  float xf[NN][4];
#pragma unroll
  for (int n = 0; n < NN; ++n) {
    const int byte = (n*2048 + kt*2) ^ ((n & 7) << 4);
    uint2 u = *(const uint2*)((char*)xt + byte);
    xf[n][0] = b2f((unsigned short)(u.x & 0xFFFF));
    xf[n][1] = b2f((unsigned short)(u.x >> 16));
    xf[n][2] = b2f((unsigned short)(u.y & 0xFFFF));
    xf[n][3] = b2f((unsigned short)(u.y >> 16));
  }
#pragma unroll
  for (int i = 0; i < NN; ++i) {
    float o0 = 0.f, o1 = 0.f, o2 = 0.f, o3 = 0.f;
#pragma unroll
    for (int n = 0; n < NN; ++n) {
      const float c = Cs[i][n];
      o0 = fmaf(c, xf[n][0], o0);
      o1 = fmaf(c, xf[n][1], o1);
      o2 = fmaf(c, xf[n][2], o2);
      o3 = fmaf(c, xf[n][3], o3);
    }
    *(float4*)(out + ((size_t)(i*RR + p))*DD + kt) = make_float4(o0, o1, o2, o3);
  }
}

extern "C" void kernel_launch(void* const* d_in, const int* in_sizes, int n_in,
                              void* d_out, int out_size, void* d_ws, size_t ws_size,
                              hipStream_t stream) {
  const float* streams = (const float*)d_in[0];
  const float* aq = (const float*)d_in[1];
  const float* ag = (const float*)d_in[2];
  const float* ab = (const float*)d_in[3];
  const float* mq = (const float*)d_in[4];
  const float* mg = (const float*)d_in[5];
  const float* mb = (const float*)d_in[6];
  float* outp = (float*)d_out;

  float* wsf   = (float*)d_ws;
  float* wvec  = wsf;
  float* scal  = wsf + OFF_SCAL;
  short* wfrag = (short*)(wsf + OFF_WFRAG);

  prep_kernel<<<dim3(2*NN), dim3(PREP_TPB), 0, stream>>>(aq, ag, ab, mq, mg, mb, wvec, scal);
  prep2_kernel<<<dim3(32), dim3(256), 0, stream>>>(wvec, wfrag);
  fused_kernel<<<dim3(RR), dim3(256), 0, stream>>>(streams, wfrag, scal, outp);
}